// Round 13
// baseline (135.849 us; speedup 1.0000x reference)
//
#include <hip/hip_runtime.h>
#include <stdint.h>

#define B_ROWS 4096
#define D_DIM  512
#define N_TOT  8192
#define TEMP_INV 2.0f   // 1/0.5
#define NB2    32       // N_TOT / 256 tiles per dim
#define NTRI2  528      // NB2*(NB2+1)/2
#define KT_N   (D_DIM / 32)  // 16 K-steps

typedef __bf16 bf16x8 __attribute__((ext_vector_type(8)));
typedef float  f32x4  __attribute__((ext_vector_type(4)));
typedef unsigned short ushort8 __attribute__((ext_vector_type(8)));

#define VM_WAIT(N) asm volatile("s_waitcnt vmcnt(" #N ")" ::: "memory")
#define LGKM0()    asm volatile("s_waitcnt lgkmcnt(0)" ::: "memory")
#define BAR()      do { asm volatile("" ::: "memory"); \
                        __builtin_amdgcn_s_barrier();  \
                        asm volatile("" ::: "memory"); } while (0)

__device__ __forceinline__ unsigned short f2bf(float f) {
    union { float f; unsigned int u; } c; c.f = f;
    unsigned int u = c.u;
    return (unsigned short)((u + 0x7fffu + ((u >> 16) & 1u)) >> 16);
}

// async global->LDS, 16B per lane. LDS dest is wave-uniform base + lane*16;
// global source is per-lane (carries the swizzle).
__device__ __forceinline__ void gl_lds16(const void* g, void* l) {
    __builtin_amdgcn_global_load_lds(
        (__attribute__((address_space(1))) void*)(uintptr_t)g,
        (__attribute__((address_space(3))) void*)(uintptr_t)l,
        16, 0, 0);
}

// ------- kernel 1: fused L2-normalize (write bf16 z) + positive-pair dot -------
__global__ __launch_bounds__(256) void normpos_kernel(
    const float* __restrict__ xi, const float* __restrict__ xj,
    unsigned short* __restrict__ z, float* __restrict__ pos,
    float* __restrict__ rowsum) {
    if (blockIdx.x < N_TOT / 256) rowsum[blockIdx.x * 256 + threadIdx.x] = 0.f;
    const int wid  = threadIdx.x >> 6;
    const int lane = threadIdx.x & 63;
    const int k    = blockIdx.x * 4 + wid;
    const float4* a4 = (const float4*)(xi + (size_t)k * D_DIM);
    const float4* b4 = (const float4*)(xj + (size_t)k * D_DIM);
    float4 va0 = a4[2 * lane], va1 = a4[2 * lane + 1];
    float4 vb0 = b4[2 * lane], vb1 = b4[2 * lane + 1];
    float ssa = va0.x*va0.x + va0.y*va0.y + va0.z*va0.z + va0.w*va0.w
              + va1.x*va1.x + va1.y*va1.y + va1.z*va1.z + va1.w*va1.w;
    float ssb = vb0.x*vb0.x + vb0.y*vb0.y + vb0.z*vb0.z + vb0.w*vb0.w
              + vb1.x*vb1.x + vb1.y*vb1.y + vb1.z*vb1.z + vb1.w*vb1.w;
    float dot = va0.x*vb0.x + va0.y*vb0.y + va0.z*vb0.z + va0.w*vb0.w
              + va1.x*vb1.x + va1.y*vb1.y + va1.z*vb1.z + va1.w*vb1.w;
    #pragma unroll
    for (int m = 32; m >= 1; m >>= 1) {
        ssa += __shfl_xor(ssa, m);
        ssb += __shfl_xor(ssb, m);
        dot += __shfl_xor(dot, m);
    }
    const float rna = 1.0f / fmaxf(sqrtf(ssa), 1e-12f);
    const float rnb = 1.0f / fmaxf(sqrtf(ssb), 1e-12f);
    float av[8] = {va0.x, va0.y, va0.z, va0.w, va1.x, va1.y, va1.z, va1.w};
    float bv[8] = {vb0.x, vb0.y, vb0.z, vb0.w, vb1.x, vb1.y, vb1.z, vb1.w};
    union { ushort8 v; unsigned short s[8]; } oa, ob;
    #pragma unroll
    for (int i = 0; i < 8; ++i) {
        oa.s[i] = f2bf(av[i] * rna);
        ob.s[i] = f2bf(bv[i] * rnb);
    }
    *(ushort8*)(z + (size_t)k * D_DIM + lane * 8) = oa.v;
    *(ushort8*)(z + (size_t)(k + B_ROWS) * D_DIM + lane * 8) = ob.v;
    if (lane == 0) pos[k] = dot * rna * rnb;
}

// -------- kernel 2: v13 -- 256x256 tile, v9's 3-deep counted-vmcnt skeleton --------
// Theory (r12): simrow is bound by the per-CU TCP issue/fill cost of the
// global_load_lds stream (532k instrs / 532 MB -- invariant across every ~62us
// variant; insensitive to barriers, occupancy, pipeline depth). 256x256 tiles
// halve staged bytes per FLOP (7.6 vs 15.2 KB/MFLOP): 270 MB / 270k instrs.
// Structure: 8 waves (512 thr), wave grid 4x2, 64x128 output/wave, acc[4][8]
// (128 AGPR; occupancy 25% -- proven irrelevant in v8). Triple-buffered LDS
// (96 KB), VM_WAIT(8) steady-state (tiles t+1,t+2 in flight), v9's proven
// 4-slot XOR swizzle on both sides. Diag blocks stage B redundantly from
// identical addresses (col0==row0) -> uniform 4 VMEM/wave/stage; compute
// always reads Bs.
__global__ __launch_bounds__(512, 2) void simrow_kernel(
    const unsigned short* __restrict__ z, float* __restrict__ rowsum) {
    __shared__ unsigned short As[3][256 * 32];  // 3 x 16 KB
    __shared__ unsigned short Bs[3][256 * 32];  // 3 x 16 KB
    __shared__ float rsum[256];
    __shared__ float csum[256];
    const int tid  = threadIdx.x;
    const int lane = tid & 63;
    const int wid  = tid >> 6;   // 0..7

    // map linear block id -> upper-triangular (bi, bj), bi <= bj
    const int t0 = blockIdx.x;
    int bi = (int)(NB2 + 0.5f - sqrtf((NB2 + 0.5f) * (NB2 + 0.5f) - 2.0f * t0));
    if (bi < 0) bi = 0;
    if (bi > NB2 - 1) bi = NB2 - 1;
    while (bi > 0 && (bi * NB2 - bi * (bi - 1) / 2) > t0) --bi;
    while ((bi + 1) * NB2 - (bi + 1) * bi / 2 <= t0) ++bi;
    const int bj = bi + (t0 - (bi * NB2 - bi * (bi - 1) / 2));
    const int row0 = bi * 256;
    const int col0 = bj * 256;
    const bool diag = (bi == bj);

    if (tid < 256) { rsum[tid] = 0.f; csum[tid] = 0.f; }

    const int wr = wid >> 1;    // 0..3 : 64-row band
    const int wc = wid & 1;     // 0..1 : 128-col band
    f32x4 acc[4][8] = {};

    // staging: wave wid covers rows [wid*32, wid*32+32) of the 256x32 tile via
    // 2 gl_lds (16 rows x 64B each). lane -> row-in-16 = lane>>2, chunk = lane&3.
    // source chunk = (lane&3) ^ ((row>>1)&3); row = wid*32 + h*16 + (lane>>2),
    // and wid*32, h*16 are 0 mod 16 -> (row>>1)&3 == (lane>>3)&3 for both h.
    const int r16 = lane >> 2;
    const int skc = ((lane & 3) ^ ((lane >> 3) & 3)) * 8;
    const unsigned short* gA0 = z + (size_t)(row0 + wid * 32 + r16)      * D_DIM + skc;
    const unsigned short* gA1 = z + (size_t)(row0 + wid * 32 + 16 + r16) * D_DIM + skc;
    const unsigned short* gB0 = z + (size_t)(col0 + wid * 32 + r16)      * D_DIM + skc;
    const unsigned short* gB1 = z + (size_t)(col0 + wid * 32 + 16 + r16) * D_DIM + skc;

    const int kqi = lane >> 4;         // desired global k-chunk
    const int ml  = lane & 15;
    const int sw  = (ml >> 1) & 3;     // swizzle term for this row parity
    const int slot = (kqi ^ sw) * 8;

    auto stage = [&](int buf, int kt) {   // exactly 4 VMEM ops per wave
        const int k0 = kt * 32;
        gl_lds16(gA0 + k0, &As[buf][(wid * 32) * 32]);
        gl_lds16(gA1 + k0, &As[buf][(wid * 32 + 16) * 32]);
        gl_lds16(gB0 + k0, &Bs[buf][(wid * 32) * 32]);
        gl_lds16(gB1 + k0, &Bs[buf][(wid * 32 + 16) * 32]);
    };
    auto compute = [&](int buf) {
        bf16x8 af[4], bfr[8];
        #pragma unroll
        for (int mi = 0; mi < 4; ++mi)
            af[mi] = *(const bf16x8*)&As[buf][(wr * 64 + mi * 16 + ml) * 32 + slot];
        #pragma unroll
        for (int ni = 0; ni < 8; ++ni)
            bfr[ni] = *(const bf16x8*)&Bs[buf][(wc * 128 + ni * 16 + ml) * 32 + slot];
        #pragma unroll
        for (int mi = 0; mi < 4; ++mi)
            #pragma unroll
            for (int ni = 0; ni < 8; ++ni)
                acc[mi][ni] = __builtin_amdgcn_mfma_f32_16x16x32_bf16(
                    af[mi], bfr[ni], acc[mi][ni], 0, 0, 0);
    };

    // prologue: three tiles in flight (12 VMEM/wave outstanding)
    stage(0, 0); stage(1, 1); stage(2, 2);

    for (int kt = 0; kt < KT_N - 2; ++kt) {
        VM_WAIT(8);          // tile kt landed; kt+1, kt+2 still flying
        BAR();
        compute(kt % 3);
        LGKM0();             // all ds_reads of buf kt%3 retired
        BAR();
        if (kt + 3 < KT_N) stage(kt % 3, kt + 3);
    }
    {   // kt = KT_N-2: only tile KT_N-1 still flying (4 ops)
        VM_WAIT(4);
        BAR();
        compute((KT_N - 2) % 3);
        LGKM0();
        BAR();
    }
    {   // kt = KT_N-1: drain
        VM_WAIT(0);
        BAR();
        compute((KT_N - 1) % 3);
    }

    // epilogue: e = exp(2*sim), mask diagonal; row sums always, col sums if off-diag
    const int quad = lane >> 4;
    const int cl   = lane & 15;
    float colacc[8] = {};
    #pragma unroll
    for (int mi = 0; mi < 4; ++mi) {
        #pragma unroll
        for (int r = 0; r < 4; ++r) {
            const int lrow = wr * 64 + mi * 16 + quad * 4 + r;
            const int irow = row0 + lrow;
            float s = 0.f;
            #pragma unroll
            for (int ni = 0; ni < 8; ++ni) {
                const int jcol = col0 + wc * 128 + ni * 16 + cl;
                float e = __expf(TEMP_INV * acc[mi][ni][r]);
                e = (irow == jcol) ? 0.f : e;
                s += e;
                colacc[ni] += e;
            }
            s += __shfl_xor(s, 1);
            s += __shfl_xor(s, 2);
            s += __shfl_xor(s, 4);
            s += __shfl_xor(s, 8);
            if (cl == 0) atomicAdd(&rsum[lrow], s);
        }
    }
    if (!diag) {
        #pragma unroll
        for (int ni = 0; ni < 8; ++ni) {
            float c = colacc[ni];
            c += __shfl_xor(c, 16);
            c += __shfl_xor(c, 32);
            if (quad == 0) atomicAdd(&csum[wc * 128 + ni * 16 + cl], c);
        }
    }
    __syncthreads();
    if (tid < 256) {
        atomicAdd(&rowsum[row0 + tid], rsum[tid]);
        if (!diag) atomicAdd(&rowsum[col0 + tid], csum[tid]);
    }
}

// ---------------- kernel 3: finalize scalar loss ----------------
__global__ __launch_bounds__(256) void finalize_kernel(
    const float* __restrict__ rowsum, const float* __restrict__ pos,
    float* __restrict__ out) {
    const int t = threadIdx.x;
    float s = 0.f;
    for (int i = t; i < N_TOT; i += 256) s += logf(rowsum[i]);
    float p = 0.f;
    for (int i = t; i < B_ROWS; i += 256) p += pos[i];
    #pragma unroll
    for (int m = 32; m >= 1; m >>= 1) {
        s += __shfl_xor(s, m);
        p += __shfl_xor(p, m);
    }
    __shared__ float ws[4], wp[4];
    if ((t & 63) == 0) { ws[t >> 6] = s; wp[t >> 6] = p; }
    __syncthreads();
    if (t == 0) {
        float tot = ws[0] + ws[1] + ws[2] + ws[3];
        float ptot = wp[0] + wp[1] + wp[2] + wp[3];
        // loss = mean(log denom) - (2*posSum)/(temp*N)
        out[0] = tot / (float)N_TOT - ptot * (2.0f * TEMP_INV / (float)N_TOT);
    }
}

extern "C" void kernel_launch(void* const* d_in, const int* in_sizes, int n_in,
                              void* d_out, int out_size, void* d_ws, size_t ws_size,
                              hipStream_t stream) {
    const float* xi = (const float*)d_in[0];
    const float* xj = (const float*)d_in[1];
    float* out = (float*)d_out;
    char* ws = (char*)d_ws;

    unsigned short* z = (unsigned short*)ws;                       // 8 MB bf16
    float* rowsum = (float*)(ws + (size_t)N_TOT * D_DIM * 2);      // 32 KB
    float* pos = rowsum + N_TOT;                                   // 16 KB

    normpos_kernel<<<B_ROWS / 4, 256, 0, stream>>>(xi, xj, z, pos, rowsum);
    simrow_kernel<<<NTRI2, 512, 0, stream>>>(z, rowsum);
    finalize_kernel<<<1, 256, 0, stream>>>(rowsum, pos, out);
}

// Round 14
// 130.339 us; speedup vs baseline: 1.0423x; 1.0423x over previous
//
#include <hip/hip_runtime.h>
#include <stdint.h>

#define B_ROWS 4096
#define D_DIM  512
#define N_TOT  8192
#define TEMP_INV 2.0f   // 1/0.5
#define NB     64       // N_TOT / 128 tiles per dim
#define NTRI   2080     // NB*(NB+1)/2
#define KT_N   (D_DIM / 32)  // 16 K-steps

typedef __bf16 bf16x8 __attribute__((ext_vector_type(8)));
typedef float  f32x4  __attribute__((ext_vector_type(4)));
typedef unsigned short ushort8 __attribute__((ext_vector_type(8)));

#define VM_WAIT(N) asm volatile("s_waitcnt vmcnt(" #N ")" ::: "memory")
#define LGKM0()    asm volatile("s_waitcnt lgkmcnt(0)" ::: "memory")
#define BAR()      do { asm volatile("" ::: "memory"); \
                        __builtin_amdgcn_s_barrier();  \
                        asm volatile("" ::: "memory"); } while (0)

__device__ __forceinline__ unsigned short f2bf(float f) {
    union { float f; unsigned int u; } c; c.f = f;
    unsigned int u = c.u;
    return (unsigned short)((u + 0x7fffu + ((u >> 16) & 1u)) >> 16);
}

// async global->LDS, 16B per lane. LDS dest is wave-uniform base + lane*16;
// global source is per-lane (carries the swizzle).
__device__ __forceinline__ void gl_lds16(const void* g, void* l) {
    __builtin_amdgcn_global_load_lds(
        (__attribute__((address_space(1))) void*)(uintptr_t)g,
        (__attribute__((address_space(3))) void*)(uintptr_t)l,
        16, 0, 0);
}

// ------- kernel 1: fused L2-normalize (write bf16 z) + positive-pair dot -------
// one wave per pair k; also zeroes rowsum and the completion counter
__global__ __launch_bounds__(256) void normpos_kernel(
    const float* __restrict__ xi, const float* __restrict__ xj,
    unsigned short* __restrict__ z, float* __restrict__ pos,
    float* __restrict__ rowsum, unsigned* __restrict__ done) {
    if (blockIdx.x < N_TOT / 256) rowsum[blockIdx.x * 256 + threadIdx.x] = 0.f;
    if (blockIdx.x == 0 && threadIdx.x == 0) *done = 0u;
    const int wid  = threadIdx.x >> 6;
    const int lane = threadIdx.x & 63;
    const int k    = blockIdx.x * 4 + wid;
    const float4* a4 = (const float4*)(xi + (size_t)k * D_DIM);
    const float4* b4 = (const float4*)(xj + (size_t)k * D_DIM);
    float4 va0 = a4[2 * lane], va1 = a4[2 * lane + 1];
    float4 vb0 = b4[2 * lane], vb1 = b4[2 * lane + 1];
    float ssa = va0.x*va0.x + va0.y*va0.y + va0.z*va0.z + va0.w*va0.w
              + va1.x*va1.x + va1.y*va1.y + va1.z*va1.z + va1.w*va1.w;
    float ssb = vb0.x*vb0.x + vb0.y*vb0.y + vb0.z*vb0.z + vb0.w*vb0.w
              + vb1.x*vb1.x + vb1.y*vb1.y + vb1.z*vb1.z + vb1.w*vb1.w;
    float dot = va0.x*vb0.x + va0.y*vb0.y + va0.z*vb0.z + va0.w*vb0.w
              + va1.x*vb1.x + va1.y*vb1.y + va1.z*vb1.z + va1.w*vb1.w;
    #pragma unroll
    for (int m = 32; m >= 1; m >>= 1) {
        ssa += __shfl_xor(ssa, m);
        ssb += __shfl_xor(ssb, m);
        dot += __shfl_xor(dot, m);
    }
    const float rna = 1.0f / fmaxf(sqrtf(ssa), 1e-12f);
    const float rnb = 1.0f / fmaxf(sqrtf(ssb), 1e-12f);
    float av[8] = {va0.x, va0.y, va0.z, va0.w, va1.x, va1.y, va1.z, va1.w};
    float bv[8] = {vb0.x, vb0.y, vb0.z, vb0.w, vb1.x, vb1.y, vb1.z, vb1.w};
    union { ushort8 v; unsigned short s[8]; } oa, ob;
    #pragma unroll
    for (int i = 0; i < 8; ++i) {
        oa.s[i] = f2bf(av[i] * rna);
        ob.s[i] = f2bf(bv[i] * rnb);
    }
    *(ushort8*)(z + (size_t)k * D_DIM + lane * 8) = oa.v;
    *(ushort8*)(z + (size_t)(k + B_ROWS) * D_DIM + lane * 8) = ob.v;
    if (lane == 0) pos[k] = dot * rna * rnb;
}

// -------- kernel 2: champion simrow (r12, 63us) + FENCE-FREE finalize tail --------
// v6 retried without its pathology: v6's 3x dilation came from 2080 device-scope
// __threadfence() wbl2/inv storms, not from the completion-counter merge (v6 was
// bit-correct). Here: ZERO fences. Ordering argument: rowsum updates are
// non-returning device-scope global_atomic_adds; the __syncthreads() before the
// counter bump drains vmcnt(0), which for atomics waits until they COMPLETED at
// the coherence point. So a RELAXED agent-scope done-increment observed as
// NTRI-th implies all blocks' rowsum atomics are globally complete. Last block
// re-reads rowsum via atomicAdd(p, 0.0f) (RMW at coherence point, v6-proven)
// and pos via plain loads (written by the previous kernel dispatch, v6-proven).
__global__ __launch_bounds__(512, 4) void simrow_kernel(
    const unsigned short* __restrict__ z, float* __restrict__ rowsum,
    const float* __restrict__ pos, float* __restrict__ out,
    unsigned* __restrict__ done) {
    __shared__ unsigned short As[3][128 * 32];  // 3 x 8 KB
    __shared__ unsigned short Bs[3][128 * 32];  // 3 x 8 KB
    __shared__ float rsum[128];
    __shared__ float csum[128];
    const int tid  = threadIdx.x;
    const int lane = tid & 63;
    const int wid  = tid >> 6;   // 0..7

    // map linear block id -> upper-triangular (bi, bj), bi <= bj
    const int t0 = blockIdx.x;
    int bi = (int)(NB + 0.5f - sqrtf((NB + 0.5f) * (NB + 0.5f) - 2.0f * t0));
    if (bi < 0) bi = 0;
    if (bi > NB - 1) bi = NB - 1;
    while (bi > 0 && (bi * NB - bi * (bi - 1) / 2) > t0) --bi;
    while ((bi + 1) * NB - (bi + 1) * bi / 2 <= t0) ++bi;
    const int bj = bi + (t0 - (bi * NB - bi * (bi - 1) / 2));
    const int row0 = bi * 128;
    const int col0 = bj * 128;
    const bool diag = (bi == bj);

    if (tid < 128) { rsum[tid] = 0.f; csum[tid] = 0.f; }

    const int wr = wid >> 2;    // 0..1 : 64-row band
    const int wc = wid & 3;     // 0..3 : 32-col band
    f32x4 acc[4][2] = {};

    // staging: wave wid covers rows [wid*16, wid*16+16) of the 128x32 tile.
    const int srow = wid * 16 + (lane >> 2);
    const int skc  = ((lane & 3) ^ ((lane >> 3) & 3)) * 8;
    const unsigned short* gA = z + (size_t)(row0 + srow) * D_DIM + skc;
    const unsigned short* gB = z + (size_t)(col0 + srow) * D_DIM + skc;

    const int kqi = lane >> 4;         // desired global k-chunk
    const int ml  = lane & 15;
    const int sw  = (ml >> 1) & 3;     // swizzle term for this row parity
    const int slot = (kqi ^ sw) * 8;

    auto stage = [&](int buf, int kt) {
        const int k0 = kt * 32;
        gl_lds16(gA + k0, &As[buf][(wid * 16) * 32]);
        gl_lds16(gB + k0, &Bs[buf][(wid * 16) * 32]);
    };
    auto compute = [&](int buf) {
        bf16x8 af[4], bfr[2];
        #pragma unroll
        for (int mi = 0; mi < 4; ++mi)
            af[mi] = *(const bf16x8*)&As[buf][(wr * 64 + mi * 16 + ml) * 32 + slot];
        #pragma unroll
        for (int ni = 0; ni < 2; ++ni)
            bfr[ni] = *(const bf16x8*)&Bs[buf][(wc * 32 + ni * 16 + ml) * 32 + slot];
        #pragma unroll
        for (int mi = 0; mi < 4; ++mi)
            #pragma unroll
            for (int ni = 0; ni < 2; ++ni)
                acc[mi][ni] = __builtin_amdgcn_mfma_f32_16x16x32_bf16(
                    af[mi], bfr[ni], acc[mi][ni], 0, 0, 0);
    };

    // prologue: three tiles in flight
    stage(0, 0); stage(1, 1); stage(2, 2);

    for (int kt = 0; kt < KT_N - 2; ++kt) {
        VM_WAIT(4);          // tile kt landed; kt+1, kt+2 still flying
        BAR();
        compute(kt % 3);
        LGKM0();             // all ds_reads of buf kt%3 retired
        BAR();
        if (kt + 3 < KT_N) stage(kt % 3, kt + 3);
    }
    {   // kt = KT_N-2: only tile KT_N-1 still flying (2 ops)
        VM_WAIT(2);
        BAR();
        compute((KT_N - 2) % 3);
        LGKM0();
        BAR();
    }
    {   // kt = KT_N-1: drain
        VM_WAIT(0);
        BAR();
        compute((KT_N - 1) % 3);
    }

    // epilogue: e = exp(2*sim), mask diagonal; row sums always, col sums if off-diag
    const int quad = lane >> 4;
    const int cl   = lane & 15;
    float colacc[2] = {0.f, 0.f};
    #pragma unroll
    for (int mi = 0; mi < 4; ++mi) {
        #pragma unroll
        for (int r = 0; r < 4; ++r) {
            const int lrow = wr * 64 + mi * 16 + quad * 4 + r;
            const int irow = row0 + lrow;
            float s = 0.f;
            #pragma unroll
            for (int ni = 0; ni < 2; ++ni) {
                const int jcol = col0 + wc * 32 + ni * 16 + cl;
                float e = __expf(TEMP_INV * acc[mi][ni][r]);
                e = (irow == jcol) ? 0.f : e;
                s += e;
                colacc[ni] += e;
            }
            s += __shfl_xor(s, 1);
            s += __shfl_xor(s, 2);
            s += __shfl_xor(s, 4);
            s += __shfl_xor(s, 8);
            if (cl == 0) atomicAdd(&rsum[lrow], s);
        }
    }
    if (!diag) {
        #pragma unroll
        for (int ni = 0; ni < 2; ++ni) {
            float c = colacc[ni];
            c += __shfl_xor(c, 16);
            c += __shfl_xor(c, 32);
            if (quad == 0) atomicAdd(&csum[wc * 32 + ni * 16 + cl], c);
        }
    }
    __syncthreads();
    if (tid < 128) {
        atomicAdd(&rowsum[row0 + tid], rsum[tid]);
        if (!diag) atomicAdd(&rowsum[col0 + tid], csum[tid]);
    }

    // ---- fence-free finalize tail: last block to retire computes the loss ----
    // __syncthreads() drains vmcnt(0) -> this block's rowsum atomics are complete
    // at the coherence point before tid 0 increments the counter (no fence needed).
    __syncthreads();
    __shared__ int amlast;
    if (tid == 0) {
        unsigned old = __hip_atomic_fetch_add(done, 1u, __ATOMIC_RELAXED,
                                              __HIP_MEMORY_SCOPE_AGENT);
        amlast = (old == NTRI - 1);
    }
    __syncthreads();
    if (amlast) {
        float s = 0.f;
        for (int i = tid; i < N_TOT; i += 512)
            s += logf(atomicAdd(&rowsum[i], 0.0f));   // coherent RMW read
        float p = 0.f;
        for (int i = tid; i < B_ROWS; i += 512) p += pos[i];
        #pragma unroll
        for (int m = 32; m >= 1; m >>= 1) {
            s += __shfl_xor(s, m);
            p += __shfl_xor(p, m);
        }
        __shared__ float ws[8], wp[8];
        if ((tid & 63) == 0) { ws[tid >> 6] = s; wp[tid >> 6] = p; }
        __syncthreads();
        if (tid == 0) {
            float tot = 0.f, ptot = 0.f;
            #pragma unroll
            for (int w = 0; w < 8; ++w) { tot += ws[w]; ptot += wp[w]; }
            // loss = mean(log denom) - (2*posSum)/(temp*N)
            out[0] = tot / (float)N_TOT - ptot * (2.0f * TEMP_INV / (float)N_TOT);
        }
    }
}

extern "C" void kernel_launch(void* const* d_in, const int* in_sizes, int n_in,
                              void* d_out, int out_size, void* d_ws, size_t ws_size,
                              hipStream_t stream) {
    const float* xi = (const float*)d_in[0];
    const float* xj = (const float*)d_in[1];
    float* out = (float*)d_out;
    char* ws = (char*)d_ws;

    unsigned short* z = (unsigned short*)ws;                       // 8 MB bf16
    float* rowsum = (float*)(ws + (size_t)N_TOT * D_DIM * 2);      // 32 KB
    float* pos = rowsum + N_TOT;                                   // 16 KB
    unsigned* done = (unsigned*)(pos + B_ROWS);                    // 4 B

    normpos_kernel<<<B_ROWS / 4, 256, 0, stream>>>(xi, xj, z, pos, rowsum, done);
    simrow_kernel<<<NTRI, 512, 0, stream>>>(z, rowsum, pos, out, done);
}

// Round 15
// 128.527 us; speedup vs baseline: 1.0570x; 1.0141x over previous
//
#include <hip/hip_runtime.h>
#include <stdint.h>

#define B_ROWS 4096
#define D_DIM  512
#define N_TOT  8192
#define TEMP_INV 2.0f   // 1/0.5
#define NB     64       // N_TOT / 128 tiles per dim
#define NTRI   2080     // NB*(NB+1)/2
#define KT_N   (D_DIM / 32)  // 16 K-steps
// completion-counter tree: 32 groups x 65 blocks (2080/32), padded to cachelines
#define NGRP   32
#define GRP_SZ 65
#define CTL_WORDS 1056   // 32 groups * 32-word stride + 32 spare; top at [1024]

typedef __bf16 bf16x8 __attribute__((ext_vector_type(8)));
typedef float  f32x4  __attribute__((ext_vector_type(4)));
typedef unsigned short ushort8 __attribute__((ext_vector_type(8)));

#define VM_WAIT(N) asm volatile("s_waitcnt vmcnt(" #N ")" ::: "memory")
#define LGKM0()    asm volatile("s_waitcnt lgkmcnt(0)" ::: "memory")
#define BAR()      do { asm volatile("" ::: "memory"); \
                        __builtin_amdgcn_s_barrier();  \
                        asm volatile("" ::: "memory"); } while (0)

__device__ __forceinline__ unsigned short f2bf(float f) {
    union { float f; unsigned int u; } c; c.f = f;
    unsigned int u = c.u;
    return (unsigned short)((u + 0x7fffu + ((u >> 16) & 1u)) >> 16);
}

// async global->LDS, 16B per lane. LDS dest is wave-uniform base + lane*16;
// global source is per-lane (carries the swizzle).
__device__ __forceinline__ void gl_lds16(const void* g, void* l) {
    __builtin_amdgcn_global_load_lds(
        (__attribute__((address_space(1))) void*)(uintptr_t)g,
        (__attribute__((address_space(3))) void*)(uintptr_t)l,
        16, 0, 0);
}

// ------- kernel 1: fused L2-normalize (write bf16 z) + positive-pair dot -------
// one wave per pair k; also zeroes rowsum and the completion-counter tree
__global__ __launch_bounds__(256) void normpos_kernel(
    const float* __restrict__ xi, const float* __restrict__ xj,
    unsigned short* __restrict__ z, float* __restrict__ pos,
    float* __restrict__ rowsum, unsigned* __restrict__ ctl) {
    if (blockIdx.x < N_TOT / 256) rowsum[blockIdx.x * 256 + threadIdx.x] = 0.f;
    if (blockIdx.x == 0)
        for (int i = threadIdx.x; i < CTL_WORDS; i += 256) ctl[i] = 0u;
    const int wid  = threadIdx.x >> 6;
    const int lane = threadIdx.x & 63;
    const int k    = blockIdx.x * 4 + wid;
    const float4* a4 = (const float4*)(xi + (size_t)k * D_DIM);
    const float4* b4 = (const float4*)(xj + (size_t)k * D_DIM);
    float4 va0 = a4[2 * lane], va1 = a4[2 * lane + 1];
    float4 vb0 = b4[2 * lane], vb1 = b4[2 * lane + 1];
    float ssa = va0.x*va0.x + va0.y*va0.y + va0.z*va0.z + va0.w*va0.w
              + va1.x*va1.x + va1.y*va1.y + va1.z*va1.z + va1.w*va1.w;
    float ssb = vb0.x*vb0.x + vb0.y*vb0.y + vb0.z*vb0.z + vb0.w*vb0.w
              + vb1.x*vb1.x + vb1.y*vb1.y + vb1.z*vb1.z + vb1.w*vb1.w;
    float dot = va0.x*vb0.x + va0.y*vb0.y + va0.z*vb0.z + va0.w*vb0.w
              + va1.x*vb1.x + va1.y*vb1.y + va1.z*vb1.z + va1.w*vb1.w;
    #pragma unroll
    for (int m = 32; m >= 1; m >>= 1) {
        ssa += __shfl_xor(ssa, m);
        ssb += __shfl_xor(ssb, m);
        dot += __shfl_xor(dot, m);
    }
    const float rna = 1.0f / fmaxf(sqrtf(ssa), 1e-12f);
    const float rnb = 1.0f / fmaxf(sqrtf(ssb), 1e-12f);
    float av[8] = {va0.x, va0.y, va0.z, va0.w, va1.x, va1.y, va1.z, va1.w};
    float bv[8] = {vb0.x, vb0.y, vb0.z, vb0.w, vb1.x, vb1.y, vb1.z, vb1.w};
    union { ushort8 v; unsigned short s[8]; } oa, ob;
    #pragma unroll
    for (int i = 0; i < 8; ++i) {
        oa.s[i] = f2bf(av[i] * rna);
        ob.s[i] = f2bf(bv[i] * rnb);
    }
    *(ushort8*)(z + (size_t)k * D_DIM + lane * 8) = oa.v;
    *(ushort8*)(z + (size_t)(k + B_ROWS) * D_DIM + lane * 8) = ob.v;
    if (lane == 0) pos[k] = dot * rna * rnb;
}

// -------- kernel 2: champion simrow (r12) + fence-free finalize tail, v15 --------
// v14 netted -3.2us (boundary -13, kernel dilation +9.5). Dilation theory:
// 2080 serialized same-address RMWs on the single done counter (~10-20cy each,
// memory-side) bunch at dispatch end and delay block retirement. v15 spreads
// them over a 2-level tree: 32 cacheline-padded group counters (group = t0&31,
// 65 blocks each; consecutive finishers hit DIFFERENT lines) + a 32-increment
// top counter. Ordering argument unchanged from v14, applied transitively:
// group old==64 => all 65 blocks' rowsum atomics complete (each incremented
// after its vmcnt-drained __syncthreads); top old==31 => all groups done.
__global__ __launch_bounds__(512, 4) void simrow_kernel(
    const unsigned short* __restrict__ z, float* __restrict__ rowsum,
    const float* __restrict__ pos, float* __restrict__ out,
    unsigned* __restrict__ ctl) {
    __shared__ unsigned short As[3][128 * 32];  // 3 x 8 KB
    __shared__ unsigned short Bs[3][128 * 32];  // 3 x 8 KB
    __shared__ float rsum[128];
    __shared__ float csum[128];
    const int tid  = threadIdx.x;
    const int lane = tid & 63;
    const int wid  = tid >> 6;   // 0..7

    // map linear block id -> upper-triangular (bi, bj), bi <= bj
    const int t0 = blockIdx.x;
    int bi = (int)(NB + 0.5f - sqrtf((NB + 0.5f) * (NB + 0.5f) - 2.0f * t0));
    if (bi < 0) bi = 0;
    if (bi > NB - 1) bi = NB - 1;
    while (bi > 0 && (bi * NB - bi * (bi - 1) / 2) > t0) --bi;
    while ((bi + 1) * NB - (bi + 1) * bi / 2 <= t0) ++bi;
    const int bj = bi + (t0 - (bi * NB - bi * (bi - 1) / 2));
    const int row0 = bi * 128;
    const int col0 = bj * 128;
    const bool diag = (bi == bj);

    if (tid < 128) { rsum[tid] = 0.f; csum[tid] = 0.f; }

    const int wr = wid >> 2;    // 0..1 : 64-row band
    const int wc = wid & 3;     // 0..3 : 32-col band
    f32x4 acc[4][2] = {};

    // staging: wave wid covers rows [wid*16, wid*16+16) of the 128x32 tile.
    const int srow = wid * 16 + (lane >> 2);
    const int skc  = ((lane & 3) ^ ((lane >> 3) & 3)) * 8;
    const unsigned short* gA = z + (size_t)(row0 + srow) * D_DIM + skc;
    const unsigned short* gB = z + (size_t)(col0 + srow) * D_DIM + skc;

    const int kqi = lane >> 4;         // desired global k-chunk
    const int ml  = lane & 15;
    const int sw  = (ml >> 1) & 3;     // swizzle term for this row parity
    const int slot = (kqi ^ sw) * 8;

    auto stage = [&](int buf, int kt) {
        const int k0 = kt * 32;
        gl_lds16(gA + k0, &As[buf][(wid * 16) * 32]);
        gl_lds16(gB + k0, &Bs[buf][(wid * 16) * 32]);
    };
    auto compute = [&](int buf) {
        bf16x8 af[4], bfr[2];
        #pragma unroll
        for (int mi = 0; mi < 4; ++mi)
            af[mi] = *(const bf16x8*)&As[buf][(wr * 64 + mi * 16 + ml) * 32 + slot];
        #pragma unroll
        for (int ni = 0; ni < 2; ++ni)
            bfr[ni] = *(const bf16x8*)&Bs[buf][(wc * 32 + ni * 16 + ml) * 32 + slot];
        #pragma unroll
        for (int mi = 0; mi < 4; ++mi)
            #pragma unroll
            for (int ni = 0; ni < 2; ++ni)
                acc[mi][ni] = __builtin_amdgcn_mfma_f32_16x16x32_bf16(
                    af[mi], bfr[ni], acc[mi][ni], 0, 0, 0);
    };

    // prologue: three tiles in flight
    stage(0, 0); stage(1, 1); stage(2, 2);

    for (int kt = 0; kt < KT_N - 2; ++kt) {
        VM_WAIT(4);          // tile kt landed; kt+1, kt+2 still flying
        BAR();
        compute(kt % 3);
        LGKM0();             // all ds_reads of buf kt%3 retired
        BAR();
        if (kt + 3 < KT_N) stage(kt % 3, kt + 3);
    }
    {   // kt = KT_N-2: only tile KT_N-1 still flying (2 ops)
        VM_WAIT(2);
        BAR();
        compute((KT_N - 2) % 3);
        LGKM0();
        BAR();
    }
    {   // kt = KT_N-1: drain
        VM_WAIT(0);
        BAR();
        compute((KT_N - 1) % 3);
    }

    // epilogue: e = exp(2*sim), mask diagonal; row sums always, col sums if off-diag
    const int quad = lane >> 4;
    const int cl   = lane & 15;
    float colacc[2] = {0.f, 0.f};
    #pragma unroll
    for (int mi = 0; mi < 4; ++mi) {
        #pragma unroll
        for (int r = 0; r < 4; ++r) {
            const int lrow = wr * 64 + mi * 16 + quad * 4 + r;
            const int irow = row0 + lrow;
            float s = 0.f;
            #pragma unroll
            for (int ni = 0; ni < 2; ++ni) {
                const int jcol = col0 + wc * 32 + ni * 16 + cl;
                float e = __expf(TEMP_INV * acc[mi][ni][r]);
                e = (irow == jcol) ? 0.f : e;
                s += e;
                colacc[ni] += e;
            }
            s += __shfl_xor(s, 1);
            s += __shfl_xor(s, 2);
            s += __shfl_xor(s, 4);
            s += __shfl_xor(s, 8);
            if (cl == 0) atomicAdd(&rsum[lrow], s);
        }
    }
    if (!diag) {
        #pragma unroll
        for (int ni = 0; ni < 2; ++ni) {
            float c = colacc[ni];
            c += __shfl_xor(c, 16);
            c += __shfl_xor(c, 32);
            if (quad == 0) atomicAdd(&csum[wc * 32 + ni * 16 + cl], c);
        }
    }
    __syncthreads();
    if (tid < 128) {
        atomicAdd(&rowsum[row0 + tid], rsum[tid]);
        if (!diag) atomicAdd(&rowsum[col0 + tid], csum[tid]);
    }

    // ---- fence-free finalize tail (hierarchical counter) ----
    // __syncthreads() drains vmcnt(0) -> this block's rowsum atomics are complete
    // at the coherence point before tid 0 touches the counters (no fence needed).
    __syncthreads();
    __shared__ int amlast;
    if (tid == 0) {
        amlast = 0;
        unsigned old = __hip_atomic_fetch_add(&ctl[(t0 & (NGRP - 1)) * 32], 1u,
                                              __ATOMIC_RELAXED,
                                              __HIP_MEMORY_SCOPE_AGENT);
        if (old == GRP_SZ - 1) {   // last block of this group
            unsigned top = __hip_atomic_fetch_add(&ctl[1024], 1u,
                                                  __ATOMIC_RELAXED,
                                                  __HIP_MEMORY_SCOPE_AGENT);
            amlast = (top == NGRP - 1);
        }
    }
    __syncthreads();
    if (amlast) {
        float s = 0.f;
        for (int i = tid; i < N_TOT; i += 512)
            s += logf(atomicAdd(&rowsum[i], 0.0f));   // coherent RMW read
        float p = 0.f;
        for (int i = tid; i < B_ROWS; i += 512) p += pos[i];
        #pragma unroll
        for (int m = 32; m >= 1; m >>= 1) {
            s += __shfl_xor(s, m);
            p += __shfl_xor(p, m);
        }
        __shared__ float ws[8], wp[8];
        if ((tid & 63) == 0) { ws[tid >> 6] = s; wp[tid >> 6] = p; }
        __syncthreads();
        if (tid == 0) {
            float tot = 0.f, ptot = 0.f;
            #pragma unroll
            for (int w = 0; w < 8; ++w) { tot += ws[w]; ptot += wp[w]; }
            // loss = mean(log denom) - (2*posSum)/(temp*N)
            out[0] = tot / (float)N_TOT - ptot * (2.0f * TEMP_INV / (float)N_TOT);
        }
    }
}

extern "C" void kernel_launch(void* const* d_in, const int* in_sizes, int n_in,
                              void* d_out, int out_size, void* d_ws, size_t ws_size,
                              hipStream_t stream) {
    const float* xi = (const float*)d_in[0];
    const float* xj = (const float*)d_in[1];
    float* out = (float*)d_out;
    char* ws = (char*)d_ws;

    unsigned short* z = (unsigned short*)ws;                       // 8 MB bf16
    float* rowsum = (float*)(ws + (size_t)N_TOT * D_DIM * 2);      // 32 KB
    float* pos = rowsum + N_TOT;                                   // 16 KB
    unsigned* ctl = (unsigned*)(pos + B_ROWS);                     // 4.2 KB

    normpos_kernel<<<B_ROWS / 4, 256, 0, stream>>>(xi, xj, z, pos, rowsum, ctl);
    simrow_kernel<<<NTRI, 512, 0, stream>>>(z, rowsum, pos, out, ctl);
}

// Round 16
// 126.728 us; speedup vs baseline: 1.0720x; 1.0142x over previous
//
#include <hip/hip_runtime.h>
#include <stdint.h>

#define B_ROWS 4096
#define D_DIM  512
#define N_TOT  8192
#define TEMP_INV 2.0f   // 1/0.5
#define NB     64       // N_TOT / 128 tiles per dim
#define NTRI   2080     // NB*(NB+1)/2
#define KT_N   (D_DIM / 32)  // 16 K-steps
// ctl layout (words): panel counters cnt[p] at p*32 (p=0..63, cacheline-padded),
// loss accumulator (float) at 2080, panels-done at 2112.
#define CTL_LOSS 2080
#define CTL_DONE 2112
#define CTL_WORDS 2144

typedef __bf16 bf16x8 __attribute__((ext_vector_type(8)));
typedef float  f32x4  __attribute__((ext_vector_type(4)));
typedef unsigned short ushort8 __attribute__((ext_vector_type(8)));

#define VM_WAIT(N) asm volatile("s_waitcnt vmcnt(" #N ")" ::: "memory")
#define LGKM0()    asm volatile("s_waitcnt lgkmcnt(0)" ::: "memory")
#define BAR()      do { asm volatile("" ::: "memory"); \
                        __builtin_amdgcn_s_barrier();  \
                        asm volatile("" ::: "memory"); } while (0)

__device__ __forceinline__ unsigned short f2bf(float f) {
    union { float f; unsigned int u; } c; c.f = f;
    unsigned int u = c.u;
    return (unsigned short)((u + 0x7fffu + ((u >> 16) & 1u)) >> 16);
}

// async global->LDS, 16B per lane. LDS dest is wave-uniform base + lane*16;
// global source is per-lane (carries the swizzle).
__device__ __forceinline__ void gl_lds16(const void* g, void* l) {
    __builtin_amdgcn_global_load_lds(
        (__attribute__((address_space(1))) void*)(uintptr_t)g,
        (__attribute__((address_space(3))) void*)(uintptr_t)l,
        16, 0, 0);
}

// ------- kernel 1: fused L2-normalize (write bf16 z) + positive-pair dot -------
// one wave per pair k; also zeroes rowsum and the ctl block
__global__ __launch_bounds__(256) void normpos_kernel(
    const float* __restrict__ xi, const float* __restrict__ xj,
    unsigned short* __restrict__ z, float* __restrict__ pos,
    float* __restrict__ rowsum, unsigned* __restrict__ ctl) {
    if (blockIdx.x < N_TOT / 256) rowsum[blockIdx.x * 256 + threadIdx.x] = 0.f;
    if (blockIdx.x == 0)
        for (int i = threadIdx.x; i < CTL_WORDS; i += 256) ctl[i] = 0u;
    const int wid  = threadIdx.x >> 6;
    const int lane = threadIdx.x & 63;
    const int k    = blockIdx.x * 4 + wid;
    const float4* a4 = (const float4*)(xi + (size_t)k * D_DIM);
    const float4* b4 = (const float4*)(xj + (size_t)k * D_DIM);
    float4 va0 = a4[2 * lane], va1 = a4[2 * lane + 1];
    float4 vb0 = b4[2 * lane], vb1 = b4[2 * lane + 1];
    float ssa = va0.x*va0.x + va0.y*va0.y + va0.z*va0.z + va0.w*va0.w
              + va1.x*va1.x + va1.y*va1.y + va1.z*va1.z + va1.w*va1.w;
    float ssb = vb0.x*vb0.x + vb0.y*vb0.y + vb0.z*vb0.z + vb0.w*vb0.w
              + vb1.x*vb1.x + vb1.y*vb1.y + vb1.z*vb1.z + vb1.w*vb1.w;
    float dot = va0.x*vb0.x + va0.y*vb0.y + va0.z*vb0.z + va0.w*vb0.w
              + va1.x*vb1.x + va1.y*vb1.y + va1.z*vb1.z + va1.w*vb1.w;
    #pragma unroll
    for (int m = 32; m >= 1; m >>= 1) {
        ssa += __shfl_xor(ssa, m);
        ssb += __shfl_xor(ssb, m);
        dot += __shfl_xor(dot, m);
    }
    const float rna = 1.0f / fmaxf(sqrtf(ssa), 1e-12f);
    const float rnb = 1.0f / fmaxf(sqrtf(ssb), 1e-12f);
    float av[8] = {va0.x, va0.y, va0.z, va0.w, va1.x, va1.y, va1.z, va1.w};
    float bv[8] = {vb0.x, vb0.y, vb0.z, vb0.w, vb1.x, vb1.y, vb1.z, vb1.w};
    union { ushort8 v; unsigned short s[8]; } oa, ob;
    #pragma unroll
    for (int i = 0; i < 8; ++i) {
        oa.s[i] = f2bf(av[i] * rna);
        ob.s[i] = f2bf(bv[i] * rnb);
    }
    *(ushort8*)(z + (size_t)k * D_DIM + lane * 8) = oa.v;
    *(ushort8*)(z + (size_t)(k + B_ROWS) * D_DIM + lane * 8) = ob.v;
    if (lane == 0) pos[k] = dot * rna * rnb;
}

// -------- kernel 2: champion simrow + PANEL-DISTRIBUTED fence-free finalize --------
// v15's serial last-block finalize (~5us while 255 CUs idle) is spread across the
// tail shadow: panel p's rowsum entries are final when the 64 tiles touching band
// p have retired (cnt[p] hits 64) -- which happens progressively, not only at
// dispatch end. The finishing block computes that panel's 128-row log-sum and
// float-atomicAdds it to a loss accumulator; the 64th finisher adds the pos term
// and writes out. Ordering (all fence-free, per v14's argument): each counter
// increment is preceded by a vmcnt-drained __syncthreads, so cnt[p]==64 implies
// all rowsum atomics for panel p are complete at the coherence point; each
// finisher's lossacc add is vmcnt-drained before its done-increment.
__global__ __launch_bounds__(512, 4) void simrow_kernel(
    const unsigned short* __restrict__ z, float* __restrict__ rowsum,
    const float* __restrict__ pos, float* __restrict__ out,
    unsigned* __restrict__ ctl) {
    __shared__ unsigned short As[3][128 * 32];  // 3 x 8 KB
    __shared__ unsigned short Bs[3][128 * 32];  // 3 x 8 KB
    __shared__ float rsum[128];
    __shared__ float csum[128];
    __shared__ float pw[8];
    __shared__ int f1s, f2s, lastf;
    const int tid  = threadIdx.x;
    const int lane = tid & 63;
    const int wid  = tid >> 6;   // 0..7

    // map linear block id -> upper-triangular (bi, bj), bi <= bj
    const int t0 = blockIdx.x;
    int bi = (int)(NB + 0.5f - sqrtf((NB + 0.5f) * (NB + 0.5f) - 2.0f * t0));
    if (bi < 0) bi = 0;
    if (bi > NB - 1) bi = NB - 1;
    while (bi > 0 && (bi * NB - bi * (bi - 1) / 2) > t0) --bi;
    while ((bi + 1) * NB - (bi + 1) * bi / 2 <= t0) ++bi;
    const int bj = bi + (t0 - (bi * NB - bi * (bi - 1) / 2));
    const int row0 = bi * 128;
    const int col0 = bj * 128;
    const bool diag = (bi == bj);

    if (tid < 128) { rsum[tid] = 0.f; csum[tid] = 0.f; }

    const int wr = wid >> 2;    // 0..1 : 64-row band
    const int wc = wid & 3;     // 0..3 : 32-col band
    f32x4 acc[4][2] = {};

    // staging: wave wid covers rows [wid*16, wid*16+16) of the 128x32 tile.
    const int srow = wid * 16 + (lane >> 2);
    const int skc  = ((lane & 3) ^ ((lane >> 3) & 3)) * 8;
    const unsigned short* gA = z + (size_t)(row0 + srow) * D_DIM + skc;
    const unsigned short* gB = z + (size_t)(col0 + srow) * D_DIM + skc;

    const int kqi = lane >> 4;         // desired global k-chunk
    const int ml  = lane & 15;
    const int sw  = (ml >> 1) & 3;     // swizzle term for this row parity
    const int slot = (kqi ^ sw) * 8;

    auto stage = [&](int buf, int kt) {
        const int k0 = kt * 32;
        gl_lds16(gA + k0, &As[buf][(wid * 16) * 32]);
        gl_lds16(gB + k0, &Bs[buf][(wid * 16) * 32]);
    };
    auto compute = [&](int buf) {
        bf16x8 af[4], bfr[2];
        #pragma unroll
        for (int mi = 0; mi < 4; ++mi)
            af[mi] = *(const bf16x8*)&As[buf][(wr * 64 + mi * 16 + ml) * 32 + slot];
        #pragma unroll
        for (int ni = 0; ni < 2; ++ni)
            bfr[ni] = *(const bf16x8*)&Bs[buf][(wc * 32 + ni * 16 + ml) * 32 + slot];
        #pragma unroll
        for (int mi = 0; mi < 4; ++mi)
            #pragma unroll
            for (int ni = 0; ni < 2; ++ni)
                acc[mi][ni] = __builtin_amdgcn_mfma_f32_16x16x32_bf16(
                    af[mi], bfr[ni], acc[mi][ni], 0, 0, 0);
    };

    // prologue: three tiles in flight
    stage(0, 0); stage(1, 1); stage(2, 2);

    for (int kt = 0; kt < KT_N - 2; ++kt) {
        VM_WAIT(4);          // tile kt landed; kt+1, kt+2 still flying
        BAR();
        compute(kt % 3);
        LGKM0();             // all ds_reads of buf kt%3 retired
        BAR();
        if (kt + 3 < KT_N) stage(kt % 3, kt + 3);
    }
    {   // kt = KT_N-2: only tile KT_N-1 still flying (2 ops)
        VM_WAIT(2);
        BAR();
        compute((KT_N - 2) % 3);
        LGKM0();
        BAR();
    }
    {   // kt = KT_N-1: drain
        VM_WAIT(0);
        BAR();
        compute((KT_N - 1) % 3);
    }

    // epilogue: e = exp(2*sim), mask diagonal; row sums always, col sums if off-diag
    const int quad = lane >> 4;
    const int cl   = lane & 15;
    float colacc[2] = {0.f, 0.f};
    #pragma unroll
    for (int mi = 0; mi < 4; ++mi) {
        #pragma unroll
        for (int r = 0; r < 4; ++r) {
            const int lrow = wr * 64 + mi * 16 + quad * 4 + r;
            const int irow = row0 + lrow;
            float s = 0.f;
            #pragma unroll
            for (int ni = 0; ni < 2; ++ni) {
                const int jcol = col0 + wc * 32 + ni * 16 + cl;
                float e = __expf(TEMP_INV * acc[mi][ni][r]);
                e = (irow == jcol) ? 0.f : e;
                s += e;
                colacc[ni] += e;
            }
            s += __shfl_xor(s, 1);
            s += __shfl_xor(s, 2);
            s += __shfl_xor(s, 4);
            s += __shfl_xor(s, 8);
            if (cl == 0) atomicAdd(&rsum[lrow], s);
        }
    }
    if (!diag) {
        #pragma unroll
        for (int ni = 0; ni < 2; ++ni) {
            float c = colacc[ni];
            c += __shfl_xor(c, 16);
            c += __shfl_xor(c, 32);
            if (quad == 0) atomicAdd(&csum[wc * 32 + ni * 16 + cl], c);
        }
    }
    __syncthreads();
    if (tid < 128) {
        atomicAdd(&rowsum[row0 + tid], rsum[tid]);
        if (!diag) atomicAdd(&rowsum[col0 + tid], csum[tid]);
    }

    // ---- panel-distributed fence-free finalize ----
    // __syncthreads drains vmcnt(0): this block's rowsum atomics are complete at
    // the coherence point before the panel-counter increments.
    __syncthreads();
    if (tid == 0) {
        unsigned o1 = __hip_atomic_fetch_add(&ctl[bi * 32], 1u, __ATOMIC_RELAXED,
                                             __HIP_MEMORY_SCOPE_AGENT);
        f1s = (o1 == NB - 1);
        f2s = 0;
        if (!diag) {
            unsigned o2 = __hip_atomic_fetch_add(&ctl[bj * 32], 1u,
                                                 __ATOMIC_RELAXED,
                                                 __HIP_MEMORY_SCOPE_AGENT);
            f2s = (o2 == NB - 1);
        }
    }
    __syncthreads();

    auto finish_panel = [&](int p) {
        // panel p final: compute sum(log(rowsum[128p .. 128p+128))) and add to
        // the loss accumulator; 64th finisher adds pos term and writes out.
        float part = 0.f;
        if (tid < 128)
            part = logf(atomicAdd(&rowsum[p * 128 + tid], 0.0f));  // coherent RMW
        #pragma unroll
        for (int m = 32; m >= 1; m >>= 1) part += __shfl_xor(part, m);
        if (lane == 0) pw[wid] = part;
        __syncthreads();
        if (tid == 0) {
            float tot = pw[0] + pw[1] + pw[2] + pw[3]
                      + pw[4] + pw[5] + pw[6] + pw[7];
            atomicAdd((float*)&ctl[CTL_LOSS], tot);   // device-scope float add
        }
        __syncthreads();   // drains vmcnt -> lossacc add complete before done++
        if (tid == 0) {
            unsigned d = __hip_atomic_fetch_add(&ctl[CTL_DONE], 1u,
                                                __ATOMIC_RELAXED,
                                                __HIP_MEMORY_SCOPE_AGENT);
            lastf = (d == NB - 1);
        }
        __syncthreads();
        if (lastf) {
            float ps = 0.f;
            for (int i = tid; i < B_ROWS; i += 512) ps += pos[i];
            #pragma unroll
            for (int m = 32; m >= 1; m >>= 1) ps += __shfl_xor(ps, m);
            if (lane == 0) pw[wid] = ps;
            __syncthreads();
            if (tid == 0) {
                float ptot = pw[0] + pw[1] + pw[2] + pw[3]
                           + pw[4] + pw[5] + pw[6] + pw[7];
                float ltot = atomicAdd((float*)&ctl[CTL_LOSS], 0.0f);
                // loss = mean(log denom) - (2*posSum)/(temp*N)
                out[0] = ltot / (float)N_TOT
                       - ptot * (2.0f * TEMP_INV / (float)N_TOT);
            }
        }
        __syncthreads();
    };

    if (f1s) finish_panel(bi);
    if (f2s) finish_panel(bj);
}

extern "C" void kernel_launch(void* const* d_in, const int* in_sizes, int n_in,
                              void* d_out, int out_size, void* d_ws, size_t ws_size,
                              hipStream_t stream) {
    const float* xi = (const float*)d_in[0];
    const float* xj = (const float*)d_in[1];
    float* out = (float*)d_out;
    char* ws = (char*)d_ws;

    unsigned short* z = (unsigned short*)ws;                       // 8 MB bf16
    float* rowsum = (float*)(ws + (size_t)N_TOT * D_DIM * 2);      // 32 KB
    float* pos = rowsum + N_TOT;                                   // 16 KB
    unsigned* ctl = (unsigned*)(pos + B_ROWS);                     // 8.6 KB

    normpos_kernel<<<B_ROWS / 4, 256, 0, stream>>>(xi, xj, z, pos, rowsum, ctl);
    simrow_kernel<<<NTRI, 512, 0, stream>>>(z, rowsum, pos, out, ctl);
}